// Round 4
// baseline (165.718 us; speedup 1.0000x reference)
//
#include <hip/hip_runtime.h>
#include <hip/hip_bf16.h>

// SubjectLayers: out[b,t,o] = sum_i x[b,t,i] * w[sid[b],i,o] + bias[sid[b],o]
// B=256 T=512 IN=256 OUT=256 S=128, all fp32 in/out.
// R4: BARRIER-FREE wave-private pipeline. Each wave owns a 32x64 output tile,
// double-buffers its own A (f32, XOR-swizzled) and B (bf16, chunk-major) in
// private LDS via global_load_lds, synced ONLY by per-wave counted vmcnt.
// Fragment loads are inline-asm ds_read_b128 fenced by hand vmcnt/lgkmcnt.

#define B_DIM 256
#define T_DIM 512
#define IN_DIM 256
#define OUT_DIM 256
#define S_DIM 128

typedef __attribute__((ext_vector_type(4))) float f32x4;
typedef __attribute__((ext_vector_type(8))) short s16x8;
typedef __attribute__((ext_vector_type(4))) unsigned short u16x4;

typedef const __attribute__((address_space(1))) unsigned int* gptr_t;
typedef __attribute__((address_space(3))) unsigned int* lptr_t;

static __device__ __forceinline__ unsigned short f2bf(float f) {
  __hip_bfloat16 h = __float2bfloat16(f);
  return __builtin_bit_cast(unsigned short, h);
}

// Pre-pass: wT[s][o][i] = bf16(w[s][i][o]). 64x64 tiles via LDS.
__global__ __launch_bounds__(256) void wt_transpose(const float* __restrict__ w,
                                                    unsigned short* __restrict__ wT) {
  __shared__ float tile[64][65];
  int bid = blockIdx.x;
  int s = bid >> 4, ti = (bid >> 2) & 3, to = bid & 3;
  const float* wp = w + (size_t)s * IN_DIM * OUT_DIM;
  unsigned short* op = wT + (size_t)s * IN_DIM * OUT_DIM;
  int t = threadIdx.x;
  int rr = t >> 6, cc = t & 63;
#pragma unroll
  for (int p = 0; p < 16; ++p) {
    tile[p * 4 + rr][cc] = wp[(size_t)(ti * 64 + p * 4 + rr) * OUT_DIM + to * 64 + cc];
  }
  __syncthreads();
  int orr = t >> 4, i4 = (t & 15) * 4;
#pragma unroll
  for (int p = 0; p < 4; ++p) {
    int ol = p * 16 + orr;  // o within tile
    u16x4 v;
    v[0] = f2bf(tile[i4 + 0][ol]);
    v[1] = f2bf(tile[i4 + 1][ol]);
    v[2] = f2bf(tile[i4 + 2][ol]);
    v[3] = f2bf(tile[i4 + 3][ol]);
    *(u16x4*)(op + (size_t)(to * 64 + ol) * IN_DIM + ti * 64 + i4) = v;
  }
}

// Wave-private pipelined GEMM. Block = 32 T-rows x 256 O-cols, 4 waves each
// owning 32x64 (2x4 frags of 16x16x32 bf16 MFMA). 8 K-steps of BK=32.
// Per wave per buffer: A = 32 rows x 128B (f32, chunk c of row r holds global
// chunk c^(r&7)); B = chunk-major, slot = chunk*64 + row (16B chunks).
__global__ __launch_bounds__(256, 2) void subj_gemm_wp(
    const float* __restrict__ x, const int* __restrict__ sid,
    const unsigned short* __restrict__ wT, const float* __restrict__ bias,
    float* __restrict__ out) {
  __shared__ __align__(16) unsigned char lds[4][2][8192];  // [wave][buf][A:4KB|B:4KB]

  // bijective XCD chunking: 4096 blocks -> 512 consecutive per XCD
  unsigned wg = blockIdx.x;
  unsigned bid = (wg & 7u) * 512u + (wg >> 3);
  int batch = bid >> 4;   // 16 m-tiles per batch
  int mtile = bid & 15;
  int s = sid[batch];

  int t = threadIdx.x;
  int l = t & 63, wv = t >> 6;

  const float* xbase = x + ((size_t)batch * T_DIM + mtile * 32) * IN_DIM;
  const unsigned short* wbase = wT + ((size_t)s * OUT_DIM + wv * 64) * IN_DIM;

  // staging lane params
  int a_row = l >> 3;                    // row within instr's 8 rows
  int a_chunk = (l & 7) ^ a_row;         // pre-swizzled source chunk (16B)
  // A src (f32): xbase + (i*8 + a_row)*IN + step*32 + a_chunk*4
  // B src (u16): wbase + l*IN + step*32 + i*8   (chunk-major: instr i = chunk i)

#define STAGEA(buf, stp, i)                                                   \
  __builtin_amdgcn_global_load_lds(                                           \
      (gptr_t)(xbase + (size_t)((i) * 8 + a_row) * IN_DIM + (stp) * 32 +      \
               a_chunk * 4),                                                  \
      (lptr_t)(lds[wv][buf] + (i) * 1024), 16, 0, 0)
#define STAGEB(buf, stp, i)                                                   \
  __builtin_amdgcn_global_load_lds(                                           \
      (gptr_t)(wbase + (size_t)l * IN_DIM + (stp) * 32 + (i) * 8),            \
      (lptr_t)(lds[wv][buf] + 4096 + (i) * 1024), 16, 0, 0)
#define STAGE(buf, stp)                                                       \
  do {                                                                        \
    STAGEA(buf, stp, 0); STAGEA(buf, stp, 1);                                 \
    STAGEA(buf, stp, 2); STAGEA(buf, stp, 3);                                 \
    STAGEB(buf, stp, 0); STAGEB(buf, stp, 1);                                 \
    STAGEB(buf, stp, 2); STAGEB(buf, stp, 3);                                 \
  } while (0)

  int fr = l & 15, kq = l >> 4;
  int r0 = kq * 4;  // C/D row group

  // read offsets (bytes within wave's 16KB region; +buf*8192 at use)
  unsigned wavebase = (unsigned)(size_t)(lptr_t)&lds[wv][0][0];
  unsigned aoff[2][2], boff[4];
#pragma unroll
  for (int fm = 0; fm < 2; ++fm) {
    int row = fm * 16 + fr;
    aoff[fm][0] = row * 128 + (((2 * kq) ^ (fr & 7)) << 4);
    aoff[fm][1] = row * 128 + (((2 * kq + 1) ^ (fr & 7)) << 4);
  }
#pragma unroll
  for (int fn = 0; fn < 4; ++fn) boff[fn] = 4096 + kq * 1024 + fn * 256 + fr * 16;

  f32x4 acc[2][4];
#pragma unroll
  for (int i = 0; i < 2; ++i)
#pragma unroll
    for (int j = 0; j < 4; ++j) acc[i][j] = (f32x4){0.f, 0.f, 0.f, 0.f};

  STAGE(0, 0);  // 8 loads
  STAGE(1, 1);  // 8 loads

#pragma unroll
  for (int stp = 0; stp < 8; ++stp) {
    const int bf = stp & 1;
    const unsigned base = wavebase + bf * 8192;
    // tile stp resident; tile stp+1's 8 loads stay in flight
    if (stp < 7) asm volatile("s_waitcnt vmcnt(8)" ::: "memory");
    else         asm volatile("s_waitcnt vmcnt(0)" ::: "memory");

    f32x4 alo[2], ahi[2];
    s16x8 bfrag[4];
#pragma unroll
    for (int fm = 0; fm < 2; ++fm) {
      asm volatile("ds_read_b128 %0, %1" : "=v"(alo[fm]) : "v"(base + aoff[fm][0]));
      asm volatile("ds_read_b128 %0, %1" : "=v"(ahi[fm]) : "v"(base + aoff[fm][1]));
    }
#pragma unroll
    for (int fn = 0; fn < 4; ++fn) {
      asm volatile("ds_read_b128 %0, %1" : "=v"(bfrag[fn]) : "v"(base + boff[fn]));
    }
    asm volatile("s_waitcnt lgkmcnt(0)" ::: "memory");
    __builtin_amdgcn_sched_barrier(0);

    if (stp < 6) STAGE(bf, stp + 2);  // reads retired -> safe to overwrite

    s16x8 af[2];
#pragma unroll
    for (int fm = 0; fm < 2; ++fm) {
      s16x8 a;
      a[0] = (short)f2bf(alo[fm][0]); a[1] = (short)f2bf(alo[fm][1]);
      a[2] = (short)f2bf(alo[fm][2]); a[3] = (short)f2bf(alo[fm][3]);
      a[4] = (short)f2bf(ahi[fm][0]); a[5] = (short)f2bf(ahi[fm][1]);
      a[6] = (short)f2bf(ahi[fm][2]); a[7] = (short)f2bf(ahi[fm][3]);
      af[fm] = a;
    }
#pragma unroll
    for (int fm = 0; fm < 2; ++fm)
#pragma unroll
      for (int fn = 0; fn < 4; ++fn)
        acc[fm][fn] = __builtin_amdgcn_mfma_f32_16x16x32_bf16(
            af[fm], bfrag[fn], acc[fm][fn], 0, 0, 0);
  }

  // epilogue: add bias, store (16-lane groups write 64B contiguous)
  const float* bp = bias + (size_t)s * OUT_DIM + wv * 64;
  float bv[4];
#pragma unroll
  for (int fn = 0; fn < 4; ++fn) bv[fn] = bp[fn * 16 + fr];

  float* orow =
      out + ((size_t)batch * T_DIM + mtile * 32) * OUT_DIM + wv * 64;
#pragma unroll
  for (int fm = 0; fm < 2; ++fm)
#pragma unroll
    for (int fn = 0; fn < 4; ++fn)
#pragma unroll
      for (int r = 0; r < 4; ++r)
        orow[(size_t)(fm * 16 + r0 + r) * OUT_DIM + fn * 16 + fr] =
            acc[fm][fn][r] + bv[fn];
#undef STAGE
#undef STAGEA
#undef STAGEB
}

// Emergency fallback if d_ws is too small: correct but slow.
__global__ __launch_bounds__(256) void naive_kernel(
    const float* __restrict__ x, const int* __restrict__ sid,
    const float* __restrict__ w, const float* __restrict__ bias,
    float* __restrict__ out) {
  __shared__ float lx[IN_DIM];
  size_t bt = blockIdx.x;
  int batch = (int)(bt / T_DIM);
  int s = sid[batch];
  int o = threadIdx.x;
  lx[o] = x[bt * IN_DIM + o];
  __syncthreads();
  const float* wp = w + (size_t)s * IN_DIM * OUT_DIM + o;
  float acc = bias[(size_t)s * OUT_DIM + o];
  for (int i = 0; i < IN_DIM; ++i) acc += lx[i] * wp[(size_t)i * OUT_DIM];
  out[bt * OUT_DIM + o] = acc;
}

extern "C" void kernel_launch(void* const* d_in, const int* in_sizes, int n_in,
                              void* d_out, int out_size, void* d_ws, size_t ws_size,
                              hipStream_t stream) {
  const float* x = (const float*)d_in[0];
  const int* sid = (const int*)d_in[1];
  const float* w = (const float*)d_in[2];
  const float* bias = (const float*)d_in[3];
  float* out = (float*)d_out;

  size_t need = (size_t)S_DIM * IN_DIM * OUT_DIM * sizeof(unsigned short);
  if (ws_size >= need) {
    unsigned short* wT = (unsigned short*)d_ws;
    wt_transpose<<<dim3(S_DIM * 16), dim3(256), 0, stream>>>(w, wT);
    subj_gemm_wp<<<dim3(4096), dim3(256), 0, stream>>>(x, sid, wT, bias, out);
  } else {
    naive_kernel<<<dim3(B_DIM * T_DIM), dim3(256), 0, stream>>>(x, sid, w, bias, out);
  }
}

// Round 5
// 93.821 us; speedup vs baseline: 1.7663x; 1.7663x over previous
//
#include <hip/hip_runtime.h>
#include <hip/hip_bf16.h>

// SubjectLayers: out[b,t,o] = sum_i x[b,t,i] * w[sid[b],i,o] + bias[sid[b],o]
// B=256 T=512 IN=256 OUT=256 S=128, all fp32 in/out.
// R5 = R3 (cooperative 128x128, counted vmcnt) + fixes:
//  - B LDS chunk-major [kq][col][16B]: conflict-free ds_read_b128
//  - STAGE(k+2) issued BEFORE compute (barrier#2 right after lgkmcnt(0))
//  - epilogue stores ordered for 256B row bursts

#define B_DIM 256
#define T_DIM 512
#define IN_DIM 256
#define OUT_DIM 256
#define S_DIM 128
#define BK 32

typedef __attribute__((ext_vector_type(4))) float f32x4;
typedef __attribute__((ext_vector_type(8))) short s16x8;
typedef __attribute__((ext_vector_type(4))) unsigned short u16x4;

typedef const __attribute__((address_space(1))) unsigned int* gptr_t;
typedef __attribute__((address_space(3))) unsigned int* lptr_t;

static __device__ __forceinline__ unsigned short f2bf(float f) {
  __hip_bfloat16 h = __float2bfloat16(f);
  return __builtin_bit_cast(unsigned short, h);
}

// Pre-pass: wT[s][o][i] = bf16(w[s][i][o]). 64x64 tiles via LDS.
__global__ __launch_bounds__(256) void wt_transpose(const float* __restrict__ w,
                                                    unsigned short* __restrict__ wT) {
  __shared__ float tile[64][65];
  int bid = blockIdx.x;
  int s = bid >> 4, ti = (bid >> 2) & 3, to = bid & 3;
  const float* wp = w + (size_t)s * IN_DIM * OUT_DIM;
  unsigned short* op = wT + (size_t)s * IN_DIM * OUT_DIM;
  int t = threadIdx.x;
  int rr = t >> 6, cc = t & 63;
#pragma unroll
  for (int p = 0; p < 16; ++p) {
    tile[p * 4 + rr][cc] = wp[(size_t)(ti * 64 + p * 4 + rr) * OUT_DIM + to * 64 + cc];
  }
  __syncthreads();
  int orr = t >> 4, i4 = (t & 15) * 4;
#pragma unroll
  for (int p = 0; p < 4; ++p) {
    int ol = p * 16 + orr;  // o within tile
    u16x4 v;
    v[0] = f2bf(tile[i4 + 0][ol]);
    v[1] = f2bf(tile[i4 + 1][ol]);
    v[2] = f2bf(tile[i4 + 2][ol]);
    v[3] = f2bf(tile[i4 + 3][ol]);
    *(u16x4*)(op + (size_t)(to * 64 + ol) * IN_DIM + ti * 64 + i4) = v;
  }
}

// Pipelined GEMM. Block = 128 T-rows x 128 O-cols, 4 waves (2m x 2n),
// wave tile 64x64 (4x4 frags of 16x16x32 bf16 MFMA). 8 K-steps of BK=32.
// A LDS: row-major 128B rows, 16B chunk c of row r holds global chunk c^(r&7).
// B LDS: chunk-major [kq 0..3][col 0..127][16B] (conflict-free reads).
__global__ __launch_bounds__(256, 3) void subj_gemm_v5(
    const float* __restrict__ x, const int* __restrict__ sid,
    const unsigned short* __restrict__ wT, const float* __restrict__ bias,
    float* __restrict__ out) {
  __shared__ __align__(16) float lA[2][128 * BK];             // 16 KB x2
  __shared__ __align__(16) unsigned short lB[2][4 * 128 * 8]; // 8 KB x2

  // pair-swizzle: the two nt-tiles of one (batch,mt) are grid-adjacent
  unsigned wg = blockIdx.x;
  unsigned bid = (wg & ~15u) | ((wg & 7u) << 1) | ((wg >> 3) & 1u);
  int batch = bid >> 3;
  int mt = (bid >> 1) & 3;
  int nt = bid & 1;
  int s = sid[batch];

  int t = threadIdx.x;
  int l = t & 63, wv = t >> 6;
  int wm = (wv >> 1) * 64, wn = (wv & 1) * 64;

  const float* xbase = x + ((size_t)batch * T_DIM + mt * 128) * IN_DIM;
  const unsigned short* wbase =
      wT + (size_t)s * IN_DIM * OUT_DIM + (size_t)(nt * 128) * IN_DIM;

  int a_row = l >> 3;                 // row within instr's 8 rows
  int a_chunk = (l & 7) ^ a_row;      // pre-swizzled source 16B chunk

  // A instr i (0..15, wave does i=wv*4..+3): rows i*8+a_row, dest lA+i*1024
  // B instr j (0..7,  wave does j=wv*2..+1): k-chunk j>>1, col (j&1)*64+l,
  //   dest lB+j*1024  (chunk-major: addr = (j>>1)*2048 + ((j&1)*64+l)*16)
#define STAGEA(buf, stp, i)                                                   \
  __builtin_amdgcn_global_load_lds(                                           \
      (gptr_t)(xbase + (size_t)((i) * 8 + a_row) * IN_DIM + (stp) * BK +      \
               a_chunk * 4),                                                  \
      (lptr_t)(&lA[buf][(i) * 256]), 16, 0, 0)
#define STAGEB(buf, stp, j)                                                   \
  __builtin_amdgcn_global_load_lds(                                           \
      (gptr_t)(wbase + (size_t)(((j) & 1) * 64 + l) * IN_DIM + (stp) * BK +   \
               ((j) >> 1) * 8),                                               \
      (lptr_t)(&lB[buf][(j) * 512]), 16, 0, 0)
#define STAGE(buf, stp)                                                       \
  do {                                                                        \
    STAGEA(buf, stp, wv * 4 + 0); STAGEA(buf, stp, wv * 4 + 1);               \
    STAGEA(buf, stp, wv * 4 + 2); STAGEA(buf, stp, wv * 4 + 3);               \
    STAGEB(buf, stp, wv * 2 + 0); STAGEB(buf, stp, wv * 2 + 1);               \
  } while (0)

  int fr = l & 15, kq = l >> 4;
  int r0 = kq * 4;  // C/D row group

  unsigned aBase = (unsigned)(size_t)(lptr_t)&lA[0][0];
  unsigned bBase = (unsigned)(size_t)(lptr_t)&lB[0][0];
  unsigned aoff[4][2], boff[4];
#pragma unroll
  for (int fm = 0; fm < 4; ++fm) {
    int row = wm + fm * 16 + fr;
    aoff[fm][0] = row * 128 + (((2 * kq) ^ (fr & 7)) << 4);
    aoff[fm][1] = row * 128 + (((2 * kq + 1) ^ (fr & 7)) << 4);
  }
#pragma unroll
  for (int fn = 0; fn < 4; ++fn)
    boff[fn] = kq * 2048 + (wn + fn * 16 + fr) * 16;

  f32x4 acc[4][4];
#pragma unroll
  for (int i = 0; i < 4; ++i)
#pragma unroll
    for (int j = 0; j < 4; ++j) acc[i][j] = (f32x4){0.f, 0.f, 0.f, 0.f};

  STAGE(0, 0);  // 6 loads/wave
  STAGE(1, 1);  // 6 loads/wave

#pragma unroll
  for (int stp = 0; stp < 8; ++stp) {
    const int bf = stp & 1;
    const unsigned ab = aBase + bf * (128 * BK * 4);
    const unsigned bb = bBase + bf * (4 * 128 * 16);
    // tile stp resident (own loads); next tile's 6 stay in flight
    if (stp < 7) asm volatile("s_waitcnt vmcnt(6)" ::: "memory");
    else         asm volatile("s_waitcnt vmcnt(0)" ::: "memory");
    asm volatile("s_barrier" ::: "memory");  // all waves' loads for stp done

    f32x4 alo[4], ahi[4];
    s16x8 bfrag[4];
#pragma unroll
    for (int fm = 0; fm < 4; ++fm) {
      asm volatile("ds_read_b128 %0, %1" : "=v"(alo[fm]) : "v"(ab + aoff[fm][0]));
      asm volatile("ds_read_b128 %0, %1" : "=v"(ahi[fm]) : "v"(ab + aoff[fm][1]));
    }
#pragma unroll
    for (int fn = 0; fn < 4; ++fn) {
      asm volatile("ds_read_b128 %0, %1" : "=v"(bfrag[fn]) : "v"(bb + boff[fn]));
    }
    asm volatile("s_waitcnt lgkmcnt(0)" ::: "memory");
    __builtin_amdgcn_sched_barrier(0);
    asm volatile("s_barrier" ::: "memory");  // all waves done reading buf bf

    if (stp < 6) STAGE(bf, stp + 2);  // issue BEFORE compute: 2-step budget

    s16x8 af[4];
#pragma unroll
    for (int fm = 0; fm < 4; ++fm) {
      s16x8 a;
      a[0] = (short)f2bf(alo[fm][0]); a[1] = (short)f2bf(alo[fm][1]);
      a[2] = (short)f2bf(alo[fm][2]); a[3] = (short)f2bf(alo[fm][3]);
      a[4] = (short)f2bf(ahi[fm][0]); a[5] = (short)f2bf(ahi[fm][1]);
      a[6] = (short)f2bf(ahi[fm][2]); a[7] = (short)f2bf(ahi[fm][3]);
      af[fm] = a;
    }
#pragma unroll
    for (int fm = 0; fm < 4; ++fm)
#pragma unroll
      for (int fn = 0; fn < 4; ++fn)
        acc[fm][fn] = __builtin_amdgcn_mfma_f32_16x16x32_bf16(
            af[fm], bfrag[fn], acc[fm][fn], 0, 0, 0);
  }

  // epilogue: add bias; store ordered fm -> r -> fn (256B row bursts)
  const float* bp = bias + (size_t)s * OUT_DIM;
  float bv[4];
#pragma unroll
  for (int fn = 0; fn < 4; ++fn) bv[fn] = bp[nt * 128 + wn + fn * 16 + fr];

  float* orow =
      out + ((size_t)batch * T_DIM + mt * 128 + wm) * OUT_DIM + nt * 128 + wn;
#pragma unroll
  for (int fm = 0; fm < 4; ++fm)
#pragma unroll
    for (int r = 0; r < 4; ++r)
#pragma unroll
      for (int fn = 0; fn < 4; ++fn)
        orow[(size_t)(fm * 16 + r0 + r) * OUT_DIM + fn * 16 + fr] =
            acc[fm][fn][r] + bv[fn];
#undef STAGE
#undef STAGEA
#undef STAGEB
}

// Emergency fallback if d_ws is too small: correct but slow.
__global__ __launch_bounds__(256) void naive_kernel(
    const float* __restrict__ x, const int* __restrict__ sid,
    const float* __restrict__ w, const float* __restrict__ bias,
    float* __restrict__ out) {
  __shared__ float lx[IN_DIM];
  size_t bt = blockIdx.x;
  int batch = (int)(bt / T_DIM);
  int s = sid[batch];
  int o = threadIdx.x;
  lx[o] = x[bt * IN_DIM + o];
  __syncthreads();
  const float* wp = w + (size_t)s * IN_DIM * OUT_DIM + o;
  float acc = bias[(size_t)s * OUT_DIM + o];
  for (int i = 0; i < IN_DIM; ++i) acc += lx[i] * wp[(size_t)i * OUT_DIM];
  out[bt * OUT_DIM + o] = acc;
}

extern "C" void kernel_launch(void* const* d_in, const int* in_sizes, int n_in,
                              void* d_out, int out_size, void* d_ws, size_t ws_size,
                              hipStream_t stream) {
  const float* x = (const float*)d_in[0];
  const int* sid = (const int*)d_in[1];
  const float* w = (const float*)d_in[2];
  const float* bias = (const float*)d_in[3];
  float* out = (float*)d_out;

  size_t need = (size_t)S_DIM * IN_DIM * OUT_DIM * sizeof(unsigned short);
  if (ws_size >= need) {
    unsigned short* wT = (unsigned short*)d_ws;
    wt_transpose<<<dim3(S_DIM * 16), dim3(256), 0, stream>>>(w, wT);
    subj_gemm_v5<<<dim3(2048), dim3(256), 0, stream>>>(x, sid, wT, bias, out);
  } else {
    naive_kernel<<<dim3(B_DIM * T_DIM), dim3(256), 0, stream>>>(x, sid, w, bias, out);
  }
}

// Round 6
// 86.949 us; speedup vs baseline: 1.9059x; 1.0790x over previous
//
#include <hip/hip_runtime.h>
#include <hip/hip_bf16.h>

// SubjectLayers: out[b,t,o] = sum_i x[b,t,i] * w[sid[b],i,o] + bias[sid[b],o]
// B=256 T=512 IN=256 OUT=256 S=128, all fp32 in/out.
// R6: LDS-byte-minimized pipeline (diagnosis: R5 was LDS-BW bound).
//  - Block = 128 rows x 256 cols (full OUT): no A duplication across blocks.
//  - A reg-staged f32->bf16 BEFORE LDS (half the LDS bytes, cvt once).
//  - B via global_load_lds, chunk-major (conflict-free reads).
//  - Depth-2 pipeline, counted vmcnt per step (queue-traced), barriers raw.

#define B_DIM 256
#define T_DIM 512
#define IN_DIM 256
#define OUT_DIM 256
#define S_DIM 128
#define BK 32

typedef __attribute__((ext_vector_type(4))) float f32x4;
typedef __attribute__((ext_vector_type(8))) short s16x8;
typedef __attribute__((ext_vector_type(4))) unsigned short u16x4;

typedef const __attribute__((address_space(1))) unsigned int* gptr_t;
typedef __attribute__((address_space(3))) unsigned int* lptr_t;

static __device__ __forceinline__ unsigned short f2bf(float f) {
  __hip_bfloat16 h = __float2bfloat16(f);
  return __builtin_bit_cast(unsigned short, h);
}

// Pre-pass: wT[s][o][i] = bf16(w[s][i][o]). 64x64 tiles via LDS.
__global__ __launch_bounds__(256) void wt_transpose(const float* __restrict__ w,
                                                    unsigned short* __restrict__ wT) {
  __shared__ float tile[64][65];
  int bid = blockIdx.x;
  int s = bid >> 4, ti = (bid >> 2) & 3, to = bid & 3;
  const float* wp = w + (size_t)s * IN_DIM * OUT_DIM;
  unsigned short* op = wT + (size_t)s * IN_DIM * OUT_DIM;
  int t = threadIdx.x;
  int rr = t >> 6, cc = t & 63;
#pragma unroll
  for (int p = 0; p < 16; ++p) {
    tile[p * 4 + rr][cc] = wp[(size_t)(ti * 64 + p * 4 + rr) * OUT_DIM + to * 64 + cc];
  }
  __syncthreads();
  int orr = t >> 4, i4 = (t & 15) * 4;
#pragma unroll
  for (int p = 0; p < 4; ++p) {
    int ol = p * 16 + orr;  // o within tile
    u16x4 v;
    v[0] = f2bf(tile[i4 + 0][ol]);
    v[1] = f2bf(tile[i4 + 1][ol]);
    v[2] = f2bf(tile[i4 + 2][ol]);
    v[3] = f2bf(tile[i4 + 3][ol]);
    *(u16x4*)(op + (size_t)(to * 64 + ol) * IN_DIM + ti * 64 + i4) = v;
  }
}

// Block = 128 T-rows x 256 O-cols, 4 waves (2m x 2n), wave tile 64x128
// (4m x 8n frags of 16x16x32 bf16 MFMA). 8 K-steps of BK=32.
// A LDS (bf16): row r (64B), 16B chunk at byte r*64 + (c ^ ((r>>1)&3))*16.
// B LDS (bf16): chunk-major, byte = kq*4096 + col*16 (kq = k/8 within step).
__global__ __launch_bounds__(256, 2) void subj_gemm_v6(
    const float* __restrict__ x, const int* __restrict__ sid,
    const unsigned short* __restrict__ wT, const float* __restrict__ bias,
    float* __restrict__ out) {
  __shared__ __align__(16) unsigned short lA[2][128 * BK];      // 8 KB x2
  __shared__ __align__(16) unsigned short lB[2][4 * OUT_DIM * 8];  // 16 KB x2

  // bijective XCD chunking: 1024 blocks -> 128 consecutive per XCD
  unsigned wg = blockIdx.x;
  unsigned bid = (wg & 7u) * 128u + (wg >> 3);
  int batch = bid >> 2;
  int mt = bid & 3;
  int s = sid[batch];

  int t = threadIdx.x;
  int l = t & 63, wv = t >> 6;
  int wm = (wv >> 1) * 64, wn = (wv & 1) * 128;

  const float* xbase = x + ((size_t)batch * T_DIM + mt * 128) * IN_DIM;
  const unsigned short* wbase = wT + (size_t)s * IN_DIM * OUT_DIM;

  // ---- A reg staging: thread t, i=0..3: row=i*32+(t>>3), f32 cols (t&7)*4..+3
  const float* ag = xbase + (size_t)(t >> 3) * IN_DIM + (t & 7) * 4;
  // A ds_write byte offset (swizzled 16B chunk, 8B half): +i*2048 per i
  const unsigned awr = (unsigned)(t >> 3) * 64 +
                       (((((t & 7) >> 1) ^ ((t >> 4) & 3))) << 4) + (t & 1) * 8;

  f32x4 areg[4], areg2[4];

#define ISSUE_A(dst, stp)                                                     \
  do {                                                                        \
    _Pragma("unroll") for (int i = 0; i < 4; ++i)                             \
        dst[i] = *(const f32x4*)(ag + (size_t)i * 32 * IN_DIM + (stp) * BK);  \
  } while (0)
#define CVT_WRITE(src, bufi)                                                  \
  do {                                                                        \
    _Pragma("unroll") for (int i = 0; i < 4; ++i) {                           \
      u16x4 h;                                                                \
      h[0] = f2bf(src[i][0]); h[1] = f2bf(src[i][1]);                         \
      h[2] = f2bf(src[i][2]); h[3] = f2bf(src[i][3]);                         \
      *(u16x4*)((unsigned char*)&lA[bufi][0] + awr + i * 2048) = h;           \
    }                                                                         \
  } while (0)
  // ---- B staging: wave wv stages k-chunk kq=wv, cols jj*64+l (jj=0..3)
#define ISSUE_B(bufi, stp)                                                    \
  do {                                                                        \
    _Pragma("unroll") for (int jj = 0; jj < 4; ++jj)                          \
        __builtin_amdgcn_global_load_lds(                                     \
            (gptr_t)(wbase + (size_t)(jj * 64 + l) * IN_DIM + (stp) * BK +    \
                     wv * 8),                                                 \
            (lptr_t)(&lB[bufi][(wv * 4 + jj) * 512]), 16, 0, 0);              \
  } while (0)

  int fr = l & 15, kq = l >> 4;
  int r0 = kq * 4;  // C/D row group

  unsigned aBase = (unsigned)(size_t)(lptr_t)&lA[0][0];
  unsigned bBase = (unsigned)(size_t)(lptr_t)&lB[0][0];
  unsigned aoff[4], boff[8];
#pragma unroll
  for (int fm = 0; fm < 4; ++fm) {
    int row = wm + fm * 16 + fr;
    aoff[fm] = row * 64 + ((kq ^ ((fr >> 1) & 3)) << 4);
  }
#pragma unroll
  for (int fn = 0; fn < 8; ++fn)
    boff[fn] = kq * 4096 + (wn + fn * 16 + fr) * 16;

  f32x4 acc[4][8];
#pragma unroll
  for (int i = 0; i < 4; ++i)
#pragma unroll
    for (int j = 0; j < 8; ++j) acc[i][j] = (f32x4){0.f, 0.f, 0.f, 0.f};

  // ---- prologue (queue invariant at loop entry: [B0, A2, B1])
  ISSUE_A(areg, 0);
  ISSUE_A(areg2, 1);
  asm volatile("s_waitcnt vmcnt(4)" ::: "memory");  // A0 ready
  CVT_WRITE(areg, 0);
  ISSUE_B(0, 0);
  asm volatile("s_waitcnt vmcnt(4)" ::: "memory");  // A1 ready, B0 in flight
  CVT_WRITE(areg2, 1);
  ISSUE_A(areg, 2);
  ISSUE_B(1, 1);
  asm volatile("s_waitcnt lgkmcnt(0)" ::: "memory");  // A0/A1 LDS writes done
  __builtin_amdgcn_sched_barrier(0);

#pragma unroll
  for (int stp = 0; stp < 8; ++stp) {
    const int bf = stp & 1;
    const unsigned ab = aBase + bf * 8192;
    const unsigned bb = bBase + bf * 16384;
    // steady queue: [B(s), A(s+2), B(s+1)] -> drain B(s) only
    if (stp < 6)       asm volatile("s_waitcnt vmcnt(8)" ::: "memory");
    else if (stp == 6) asm volatile("s_waitcnt vmcnt(4)" ::: "memory");
    else               asm volatile("s_waitcnt vmcnt(0)" ::: "memory");
    asm volatile("s_barrier" ::: "memory");  // buf[bf] fully staged

    s16x8 af[4], bfr[8];
#pragma unroll
    for (int fm = 0; fm < 4; ++fm)
      asm volatile("ds_read_b128 %0, %1" : "=v"(af[fm]) : "v"(ab + aoff[fm]));
#pragma unroll
    for (int fn = 0; fn < 8; ++fn)
      asm volatile("ds_read_b128 %0, %1" : "=v"(bfr[fn]) : "v"(bb + boff[fn]));
    asm volatile("s_waitcnt lgkmcnt(0)" ::: "memory");
    __builtin_amdgcn_sched_barrier(0);
    asm volatile("s_barrier" ::: "memory");  // all waves done reading buf[bf]

    if (stp < 6) {
      asm volatile("s_waitcnt vmcnt(4)" ::: "memory");  // A(s+2) regs ready
      CVT_WRITE(areg, bf);                              // A(s+2) -> buf[bf]
      if (stp < 5) ISSUE_A(areg, stp + 3);
      ISSUE_B(bf, stp + 2);
      __builtin_amdgcn_sched_barrier(0);
    }

#pragma unroll
    for (int fm = 0; fm < 4; ++fm)
#pragma unroll
      for (int fn = 0; fn < 8; ++fn)
        acc[fm][fn] = __builtin_amdgcn_mfma_f32_16x16x32_bf16(
            af[fm], bfr[fn], acc[fm][fn], 0, 0, 0);
  }

  // ---- epilogue: bias + store (fm -> r -> fn: 16-lane 64B bursts per fn)
  const float* bp = bias + (size_t)s * OUT_DIM;
  float bv[8];
#pragma unroll
  for (int fn = 0; fn < 8; ++fn) bv[fn] = bp[wn + fn * 16 + fr];

  float* orow = out + ((size_t)batch * T_DIM + mt * 128 + wm) * OUT_DIM + wn;
#pragma unroll
  for (int fm = 0; fm < 4; ++fm)
#pragma unroll
    for (int r = 0; r < 4; ++r)
#pragma unroll
      for (int fn = 0; fn < 8; ++fn)
        orow[(size_t)(fm * 16 + r0 + r) * OUT_DIM + fn * 16 + fr] =
            acc[fm][fn][r] + bv[fn];
#undef ISSUE_A
#undef ISSUE_B
#undef CVT_WRITE
}

// Emergency fallback if d_ws is too small: correct but slow.
__global__ __launch_bounds__(256) void naive_kernel(
    const float* __restrict__ x, const int* __restrict__ sid,
    const float* __restrict__ w, const float* __restrict__ bias,
    float* __restrict__ out) {
  __shared__ float lx[IN_DIM];
  size_t bt = blockIdx.x;
  int batch = (int)(bt / T_DIM);
  int s = sid[batch];
  int o = threadIdx.x;
  lx[o] = x[bt * IN_DIM + o];
  __syncthreads();
  const float* wp = w + (size_t)s * IN_DIM * OUT_DIM + o;
  float acc = bias[(size_t)s * OUT_DIM + o];
  for (int i = 0; i < IN_DIM; ++i) acc += lx[i] * wp[(size_t)i * OUT_DIM];
  out[bt * OUT_DIM + o] = acc;
}

extern "C" void kernel_launch(void* const* d_in, const int* in_sizes, int n_in,
                              void* d_out, int out_size, void* d_ws, size_t ws_size,
                              hipStream_t stream) {
  const float* x = (const float*)d_in[0];
  const int* sid = (const int*)d_in[1];
  const float* w = (const float*)d_in[2];
  const float* bias = (const float*)d_in[3];
  float* out = (float*)d_out;

  size_t need = (size_t)S_DIM * IN_DIM * OUT_DIM * sizeof(unsigned short);
  if (ws_size >= need) {
    unsigned short* wT = (unsigned short*)d_ws;
    wt_transpose<<<dim3(S_DIM * 16), dim3(256), 0, stream>>>(w, wT);
    subj_gemm_v6<<<dim3(1024), dim3(256), 0, stream>>>(x, sid, wT, bias, out);
  } else {
    naive_kernel<<<dim3(B_DIM * T_DIM), dim3(256), 0, stream>>>(x, sid, w, bias, out);
  }
}